// Round 9
// baseline (104.813 us; speedup 1.0000x reference)
//
#include <hip/hip_runtime.h>

// LogisticRegressionRBF: out[k] = sigmoid( sum_n w[n]*exp(-||x_k - c_n||^2) + b )
// K=65536, N=4096, M=64. fp32 in/out.
//
// R16: OCCUPANCY PLAY (from R15's A/B: halving waves/CU 16->8 cost +37% at
// constant per-CU work -> exposed latency that TLP hides; so double TLP to
// 32 waves/CU). That needs <=64 unified regs/wave (occupancy steps at
// 64/128/256). Surgery from the ~124-reg R13 wave:
//   - ONE 32x32 tile per wave (was two): acc 16 (in-place zeroed C), af 8,
//     pb ping-pong 16.
//   - p[16] C-init ELIMINATED: MFMA computes the raw dot d; screen becomes
//     conservative  max_i d[i] > tq - pmx  with pmx = -log2e*min(x^2) over
//     the wave's 32 rows (1 loop-invariant reg). Sound: skip => all
//     d[i]+p_i <= tq => log2phi <= -60. Slack ~35 log2 inflates rare-path
//     rate to ~1-3%; rare path reads exact p_i from LDS x2s (16 ds_reads +
//     exp, amortized ~3 cyc/step). Extra admitted tiles add terms the
//     reference also sums -> absmax unaffected.
// Geometry: block 512 = 2 row-tiles(32) x 4 center-quarters, 64 rows/block,
// grid 1024 = 4 blocks/CU = 32 waves/CU. __launch_bounds__(512,8) forces
// <=64 regs (WRITE_SIZE is the spill tripwire). Same MFMA count and same
// cb/hcw layout as R13. Readout: total dur (main won't crack fill-dominated
// top-5 if it works): ~68-74 win / ~88 theory-dead / >95 spills-revert.

#define KOBS 65536
#define NCENT 4096
#define MFEAT 64

#define SCALE_A 2.8853900817779268f  // 2*log2(e)
#define QS      1.4426950408889634f  // log2(e)
#define TSKIP   -60.0f

typedef __attribute__((ext_vector_type(4)))  float float4v;
typedef __attribute__((ext_vector_type(16))) float float16v;
typedef __attribute__((ext_vector_type(8)))  int   int8v;

#if __has_builtin(__builtin_amdgcn_exp2f)
#define EXP2F(x) __builtin_amdgcn_exp2f(x)
#else
#define EXP2F(x) exp2f(x)
#endif

static __device__ inline unsigned f2bfu(float f) {
    unsigned u = __float_as_uint(f);
    return (u + 0x7fffu + ((u >> 16) & 1u)) >> 16;
}

#define MFMA(A, B, C) __builtin_amdgcn_mfma_scale_f32_32x32x64_f8f6f4( \
    (A), (B), (C), 0, 0, 0, 0x7f7f7f7f, 0, 0x7f7f7f7f)

// ================================ prep =====================================
// Blocks [0,128): transpose+quantize xb fp32 -> fp8 e4m3 B-fragments.
// Blocks [128,1152): hcw[n] = { bf16(TSKIP + log2e*||c_n||^2) | bf16(w[n]) }.
__global__ __launch_bounds__(256) void rbf_prep(
    const float* __restrict__ xb, const float* __restrict__ w,
    char* __restrict__ cb, unsigned* __restrict__ hcw) {
    const int bid = blockIdx.x;
    const int tid = threadIdx.x;
    if (bid < 128) {
        const int o      = bid * 256 + tid;   // (center, k-octet), [0, 32768)
        const int col    = o >> 3;            // center index
        const int joct   = o & 7;             // k0 = joct*8
        const int c      = col >> 7;          // chunk
        const int w4     = (col >> 5) & 3;    // wave-quarter within chunk
        const int lanelo = col & 31;
        const int l      = lanelo + (joct >> 2) * 32;  // lane (k-half select)
        const int j0     = (joct & 3) * 8;             // byte offset in 32B
        const float* src = xb + col * MFEAT + joct * 8;
        float4v v0 = *(const float4v*)(src);
        float4v v1 = *(const float4v*)(src + 4);
        int lo = __builtin_amdgcn_cvt_pk_fp8_f32(v0[0], v0[1], 0, false);
        lo     = __builtin_amdgcn_cvt_pk_fp8_f32(v0[2], v0[3], lo, true);
        int hi = __builtin_amdgcn_cvt_pk_fp8_f32(v1[0], v1[1], 0, false);
        hi     = __builtin_amdgcn_cvt_pk_fp8_f32(v1[2], v1[3], hi, true);
        unsigned long long pk = (unsigned long long)(unsigned)lo |
                                ((unsigned long long)(unsigned)hi << 32);
        *(unsigned long long*)(cb + (size_t)((c * 4 + w4) * 64 + l) * 32 + j0) = pk;
    } else {
        const int row  = (bid - 128) * 4 + (tid >> 6);
        const int lane = tid & 63;
        float v = xb[row * MFEAT + lane];
        float s = v * v;
        #pragma unroll
        for (int off = 32; off > 0; off >>= 1) s += __shfl_xor(s, off, 64);
        if (lane == 0)
            hcw[row] = (f2bfu(TSKIP + QS * s) << 16) | f2bfu(w[row]);
    }
}

// ================================ main =====================================
// grid 1024 x block 512. Block: 64 output rows.
// Wave wv: rt = wv>>2 row-tile (32 rows), wq = wv&3 center quarter.
__global__ __launch_bounds__(512, 8) void rbf_main(
    const float* __restrict__ x, const char* __restrict__ cb,
    const unsigned* __restrict__ hcw, const float* __restrict__ bptr,
    float* __restrict__ out) {
    __shared__ float x2s[64];
    __shared__ float zl[64];

    const int tid  = threadIdx.x;
    const int wv   = tid >> 6;
    const int lane = tid & 63;
    const int ll   = lane & 31;
    const int lh   = lane >> 5;
    const int rt   = wv >> 2;        // row-tile (32 rows)
    const int wq   = wv & 3;         // center quarter
    const int bid  = (int)blockIdx.x;
    const int rt32 = rt * 32;
    const int rb   = 4 * lh;

    if (tid < 64) zl[tid] = 0.0f;

    // ---- A fragment (fp8, pre-scaled by 2*log2e) + row norms ----
    // A-frag layout 32x32x64: lane l holds row l&31, k = (l>>5)*32 + byte.
    int8v af;
    {
        const float* xr = x + (size_t)(bid * 64 + rt32 + ll) * MFEAT + lh * 32;
        float ss = 0.0f;
        #pragma unroll
        for (int rg = 0; rg < 8; ++rg) {
            float4v v = *(const float4v*)(xr + rg * 4);
            ss = fmaf(v[0], v[0], ss); ss = fmaf(v[1], v[1], ss);
            ss = fmaf(v[2], v[2], ss); ss = fmaf(v[3], v[3], ss);
            int pk = __builtin_amdgcn_cvt_pk_fp8_f32(
                SCALE_A * v[0], SCALE_A * v[1], 0, false);
            pk = __builtin_amdgcn_cvt_pk_fp8_f32(
                SCALE_A * v[2], SCALE_A * v[3], pk, true);
            af[rg] = pk;
        }
        ss += __shfl_xor(ss, 32, 64);   // partner lane has other k-half
        if (wq == 0 && lh == 0) x2s[rt32 + ll] = ss;
    }
    __syncthreads();

    // ---- pmx = -log2e * min(x^2) over this wave's 32 rows (1 register) ----
    float pmx;
    {
        float pv = x2s[rt32 + ll];
        pv = fminf(pv, __shfl_xor(pv, 1,  64));
        pv = fminf(pv, __shfl_xor(pv, 2,  64));
        pv = fminf(pv, __shfl_xor(pv, 4,  64));
        pv = fminf(pv, __shfl_xor(pv, 8,  64));
        pv = fminf(pv, __shfl_xor(pv, 16, 64));
        pmx = -QS * pv;
    }

    // ---- main loop: ping-pong register prefetch, literal slot indices ----
    const unsigned cboff = (unsigned)(wq * 64 + lane) * 32u;  // voffset, saddr
    const unsigned moff  = (unsigned)(wq * 32 + ll);

    int8v    pb[2];
    unsigned mw[2];

    #define LOADB(C, S) do {                                               \
        pb[S] = *(const int8v*)(cb + cboff + (unsigned)(C) * 8192u);       \
        mw[S] = hcw[moff + (unsigned)(C) * 128u];                          \
    } while (0)

    #define STEP(C, S, DOLOAD) do {                                       \
        const unsigned mu = mw[S];                                        \
        const float tq  = __uint_as_float(mu & 0xffff0000u);              \
        const float wv_ = __uint_as_float(mu << 16);                      \
        float16v d;                                                       \
        _Pragma("unroll")                                                 \
        for (int z_ = 0; z_ < 16; ++z_) d[z_] = 0.0f;                     \
        d = MFMA(af, pb[S], d);                                           \
        if (DOLOAD) LOADB((C) + 2, S);                                    \
        float u0 = fmaxf(fmaxf(d[0],  d[1]),  d[2]);                      \
        float u1 = fmaxf(fmaxf(d[3],  d[4]),  d[5]);                      \
        float u2 = fmaxf(fmaxf(d[6],  d[7]),  d[8]);                      \
        float u3 = fmaxf(fmaxf(d[9],  d[10]), d[11]);                     \
        float u4 = fmaxf(fmaxf(d[12], d[13]), d[14]);                     \
        float mxd = fmaxf(fmaxf(fmaxf(u0, u1), u2),                       \
                          fmaxf(fmaxf(u3, u4), d[15]));                   \
        const float thr = tq - pmx;        /* conservative screen */      \
        if (__any(mxd > thr)) {            /* ~1-3% of tiles */           \
            const float q = TSKIP - tq;    /* = -log2e*||c||^2 */         \
            if (mxd > thr) {                                              \
                _Pragma("unroll")                                         \
                for (int i_ = 0; i_ < 16; ++i_) {                         \
                    const int row_ = rb + (i_ & 3) + 8 * (i_ >> 2);       \
                    const float pi_ = -QS * x2s[rt32 + row_];             \
                    atomicAdd(&zl[rt32 + row_],                           \
                              wv_ * EXP2F(d[i_] + pi_ + q));              \
                }                                                         \
            }                                                             \
        }                                                                 \
    } while (0)

    LOADB(0, 0);
    LOADB(1, 1);

    #pragma unroll 1
    for (int c = 0; c < 30; c += 2) {    // steps 0..29; slot = step & 1
        STEP(c,     0, 1);
        STEP(c + 1, 1, 1);
    }
    STEP(30, 0, 0);                      // peeled, no prefetch
    STEP(31, 1, 0);

    #undef STEP
    #undef LOADB

    // ---- combine, sigmoid, store ----
    __syncthreads();
    if (tid < 64) {
        const float z = zl[tid] + bptr[0];
        out[bid * 64 + tid] = 1.0f / (1.0f + EXP2F(-QS * z));
    }
}

// ================================ launcher =================================
extern "C" void kernel_launch(void* const* d_in, const int* in_sizes, int n_in,
                              void* d_out, int out_size, void* d_ws, size_t ws_size,
                              hipStream_t stream) {
    const float* x  = (const float*)d_in[0];   // [K, M]
    const float* xb = (const float*)d_in[1];   // [N, M]
    const float* w  = (const float*)d_in[2];   // [1, N]
    const float* b  = (const float*)d_in[3];   // [1]
    float* out = (float*)d_out;                // [K]

    char*     cb  = (char*)d_ws;                               // 256 KB fp8
    unsigned* hcw = (unsigned*)((char*)d_ws + NCENT * MFEAT);  // 16 KB packed meta

    rbf_prep<<<128 + NCENT / 4, 256, 0, stream>>>(xb, w, cb, hcw);
    rbf_main<<<KOBS / 64, 512, 0, stream>>>(x, cb, hcw, b, out);
}

// Round 10
// 89.063 us; speedup vs baseline: 1.1768x; 1.1768x over previous
//
#include <hip/hip_runtime.h>

// LogisticRegressionRBF: out[k] = sigmoid( sum_n w[n]*exp(-||x_k - c_n||^2) + b )
// K=65536, N=4096, M=64. fp32 in/out.
//
// R17: LDS-staged B (canonical §5 pattern), R13 geometry + tight screen.
// R16 lessons applied: (a) loose screen = fire-rate explosion (chi-sq tail:
// 25-35 log2 slack -> O(1) of tiles take the 16-exp2+contended-atomic path)
// -> tight screen restored (C-init = -log2e*||x||^2 in MFMA, threshold
// exact); (b) occupancy is register-capped at ~16 waves/CU for every config
// with p[16]+pb+acc (64-reg cliff unreachable) -> stop chasing TLP, shorten
// the per-step stall instead:
//   - each 8 KB chunk staged into LDS ONCE per block (reg-staged: thread t
//     copies bytes t*16; coalesced 8 KB stream vs R13's scattered per-wave
//     reads with rt-duplication -> L2 traffic per block 512->256 KB)
//   - T14 split: stage-load issued at TOP of chunk c (for c+1), ds_write
//     after compute (vmcnt hidden under ~500 cyc of MFMA+screen)
//   - double-buffer, ONE barrier per chunk
//   - in-loop B access becomes 2x ds_read_b128 (~120 cyc, no L2 contention)
//   - LDS layout: 4-row groups of 128 B + 16 B pad (stride 144): 16 B
//     alignment kept, read banks spread (~2-way max = free per m136)
// Regs ~105 (same 16-wave band), LDS 19.5 KB. Tripwires: SQ_LDS_BANK_CONFLICT
// (~0 expected), WRITE_SIZE (~0.5 MB, spills).

#define KOBS 65536
#define NCENT 4096
#define MFEAT 64
#define NCHUNK 32                    // 4096 / 128 centers per chunk

#define SCALE_A 2.8853900817779268f  // 2*log2(e)
#define QS      1.4426950408889634f  // log2(e)
#define TSKIP   -60.0f

typedef __attribute__((ext_vector_type(4)))  float    float4v;
typedef __attribute__((ext_vector_type(16))) float    float16v;
typedef __attribute__((ext_vector_type(8)))  int      int8v;
typedef __attribute__((ext_vector_type(4)))  unsigned uint4v;

#if __has_builtin(__builtin_amdgcn_exp2f)
#define EXP2F(x) __builtin_amdgcn_exp2f(x)
#else
#define EXP2F(x) exp2f(x)
#endif

static __device__ inline unsigned f2bfu(float f) {
    unsigned u = __float_as_uint(f);
    return (u + 0x7fffu + ((u >> 16) & 1u)) >> 16;
}

#define MFMA(A, B, C) __builtin_amdgcn_mfma_scale_f32_32x32x64_f8f6f4( \
    (A), (B), (C), 0, 0, 0, 0x7f7f7f7f, 0, 0x7f7f7f7f)

// LDS chunk layout: row r (0..255, 32B each) at (r>>2)*144 + (r&3)*32
#define LROW(r) (((r) >> 2) * 144 + ((r) & 3) * 32)
#define LBUFSZ  (64 * 144)           // 9216 B per buffer

// ================================ prep =====================================
// Blocks [0,128): transpose+quantize xb fp32 -> fp8 e4m3 B-fragments (dense
// chunk-major). Blocks [128,1152): hcw[n] = {bf16(TSKIP+log2e*||c||^2)|bf16 w}.
__global__ __launch_bounds__(256) void rbf_prep(
    const float* __restrict__ xb, const float* __restrict__ w,
    char* __restrict__ cb, unsigned* __restrict__ hcw) {
    const int bid = blockIdx.x;
    const int tid = threadIdx.x;
    if (bid < 128) {
        const int o      = bid * 256 + tid;   // (center, k-octet), [0, 32768)
        const int col    = o >> 3;            // center index
        const int joct   = o & 7;             // k0 = joct*8
        const int c      = col >> 7;          // chunk
        const int w4     = (col >> 5) & 3;    // wave-quarter within chunk
        const int lanelo = col & 31;
        const int l      = lanelo + (joct >> 2) * 32;  // lane (k-half select)
        const int j0     = (joct & 3) * 8;             // byte offset in 32B
        const float* src = xb + col * MFEAT + joct * 8;
        float4v v0 = *(const float4v*)(src);
        float4v v1 = *(const float4v*)(src + 4);
        int lo = __builtin_amdgcn_cvt_pk_fp8_f32(v0[0], v0[1], 0, false);
        lo     = __builtin_amdgcn_cvt_pk_fp8_f32(v0[2], v0[3], lo, true);
        int hi = __builtin_amdgcn_cvt_pk_fp8_f32(v1[0], v1[1], 0, false);
        hi     = __builtin_amdgcn_cvt_pk_fp8_f32(v1[2], v1[3], hi, true);
        unsigned long long pk = (unsigned long long)(unsigned)lo |
                                ((unsigned long long)(unsigned)hi << 32);
        *(unsigned long long*)(cb + (size_t)((c * 4 + w4) * 64 + l) * 32 + j0) = pk;
    } else {
        const int row  = (bid - 128) * 4 + (tid >> 6);
        const int lane = tid & 63;
        float v = xb[row * MFEAT + lane];
        float s = v * v;
        #pragma unroll
        for (int off = 32; off > 0; off >>= 1) s += __shfl_xor(s, off, 64);
        if (lane == 0)
            hcw[row] = (f2bfu(TSKIP + QS * s) << 16) | f2bfu(w[row]);
    }
}

// ================================ main =====================================
// grid 512 x block 512. Block: 128 output rows.
// Wave wv: rt = wv>>2 row-tile (64 rows), wq = wv&3 center quarter.
__global__ __launch_bounds__(512, 4) void rbf_main(
    const float* __restrict__ x, const char* __restrict__ cb,
    const unsigned* __restrict__ hcw, const float* __restrict__ bptr,
    float* __restrict__ out) {
    __shared__ float x2s[128];
    __shared__ float zl[128];
    __shared__ char  bs[2][LBUFSZ];

    const int tid  = threadIdx.x;
    const int wv   = tid >> 6;
    const int lane = tid & 63;
    const int ll   = lane & 31;
    const int lh   = lane >> 5;
    const int rt   = wv >> 2;
    const int wq   = wv & 3;
    const int bid  = (int)blockIdx.x;

    if (tid < 128) zl[tid] = 0.0f;

    // ---- A fragments (fp8, pre-scaled by 2*log2e) + row norms ----
    // A-frag layout 32x32x64: lane l holds row l&31, k = (l>>5)*32 + byte.
    const int r0e = bid * 128 + rt * 64;
    int8v af0, af1;
    #pragma unroll
    for (int t = 0; t < 2; ++t) {
        const float* xr = x + (size_t)(r0e + t * 32 + ll) * MFEAT + lh * 32;
        int8v a;
        float ss = 0.0f;
        #pragma unroll
        for (int rg = 0; rg < 8; ++rg) {
            float4v v = *(const float4v*)(xr + rg * 4);
            ss = fmaf(v[0], v[0], ss); ss = fmaf(v[1], v[1], ss);
            ss = fmaf(v[2], v[2], ss); ss = fmaf(v[3], v[3], ss);
            int pk = __builtin_amdgcn_cvt_pk_fp8_f32(
                SCALE_A * v[0], SCALE_A * v[1], 0, false);
            pk = __builtin_amdgcn_cvt_pk_fp8_f32(
                SCALE_A * v[2], SCALE_A * v[3], pk, true);
            a[rg] = pk;
        }
        ss += __shfl_xor(ss, 32, 64);   // partner lane has other k-half
        if (t == 0) af0 = a; else af1 = a;
        if (wq == 0 && lh == 0) x2s[rt * 64 + t * 32 + ll] = ss;
    }

    // ---- stage chunk 0 into bs[0] (overlaps A-phase latency) ----
    const unsigned sdst = (unsigned)(LROW(tid >> 1) + (tid & 1) * 16);
    uint4v stg = *(const uint4v*)(cb + tid * 16);
    unsigned mw = hcw[wq * 32 + ll];             // chunk 0 meta
    *(uint4v*)(bs[0] + sdst) = stg;              // compiler waits vmcnt

    __syncthreads();   // x2s ready + bs[0] ready

    // ---- C-init: p = -log2e*||x_row||^2 in C/D layout ----
    // row = (reg&3) + 8*(reg>>2) + 4*(lane>>5)  [+ t*32]
    const int rb = 4 * lh;
    float16v p0, p1;
    #pragma unroll
    for (int i = 0; i < 16; ++i) {
        const int ri = rb + (i & 3) + 8 * (i >> 2);
        p0[i] = -QS * x2s[rt * 64 + ri];
        p1[i] = -QS * x2s[rt * 64 + 32 + ri];
    }

    // ---- main loop: LDS double-buffered B, one barrier/chunk ----
    const int zbase = rt * 64 + rb;
    const unsigned moff  = (unsigned)(wq * 32 + ll);
    const unsigned rdoff = (unsigned)LROW(wq * 64 + lane);

    #pragma unroll 1
    for (int c = 0; c < NCHUNK; ++c) {
        unsigned mwn = mw;
        if (c + 1 < NCHUNK) {                    // T14: issue-early
            stg = *(const uint4v*)(cb + (size_t)(c + 1) * 8192 + tid * 16);
            mwn = hcw[moff + (unsigned)(c + 1) * 128u];
        }
        // B fragment from LDS
        const char* lb = bs[c & 1];
        uint4v blo = *(const uint4v*)(lb + rdoff);
        uint4v bhi = *(const uint4v*)(lb + rdoff + 16);
        int8v b;
        b[0] = (int)blo[0]; b[1] = (int)blo[1]; b[2] = (int)blo[2]; b[3] = (int)blo[3];
        b[4] = (int)bhi[0]; b[5] = (int)bhi[1]; b[6] = (int)bhi[2]; b[7] = (int)bhi[3];

        float16v a0 = MFMA(af0, b, p0);
        float16v a1 = MFMA(af1, b, p1);

        const float tq  = __uint_as_float(mw & 0xffff0000u);
        const float wv_ = __uint_as_float(mw << 16);
        float uA0 = fmaxf(fmaxf(a0[0],  a0[1]),  a0[2]);
        float uA1 = fmaxf(fmaxf(a0[3],  a0[4]),  a0[5]);
        float uA2 = fmaxf(fmaxf(a0[6],  a0[7]),  a0[8]);
        float uA3 = fmaxf(fmaxf(a0[9],  a0[10]), a0[11]);
        float uA4 = fmaxf(fmaxf(a0[12], a0[13]), a0[14]);
        float mA  = fmaxf(fmaxf(fmaxf(uA0, uA1), uA2),
                          fmaxf(fmaxf(uA3, uA4), a0[15]));
        float uB0 = fmaxf(fmaxf(a1[0],  a1[1]),  a1[2]);
        float uB1 = fmaxf(fmaxf(a1[3],  a1[4]),  a1[5]);
        float uB2 = fmaxf(fmaxf(a1[6],  a1[7]),  a1[8]);
        float uB3 = fmaxf(fmaxf(a1[9],  a1[10]), a1[11]);
        float uB4 = fmaxf(fmaxf(a1[12], a1[13]), a1[14]);
        float mB  = fmaxf(fmaxf(fmaxf(uB0, uB1), uB2),
                          fmaxf(fmaxf(uB3, uB4), a1[15]));
        if (__any(fmaxf(mA, mB) > tq)) {         // rare: ~1e-4 of tiles
            const float q = TSKIP - tq;          // = -log2e*||c||^2
            if (mA > tq) {
                #pragma unroll
                for (int i_ = 0; i_ < 16; ++i_)
                    atomicAdd(&zl[zbase + (i_ & 3) + 8 * (i_ >> 2)],
                              wv_ * EXP2F(a0[i_] + q));
            }
            if (mB > tq) {
                #pragma unroll
                for (int i_ = 0; i_ < 16; ++i_)
                    atomicAdd(&zl[zbase + 32 + (i_ & 3) + 8 * (i_ >> 2)],
                              wv_ * EXP2F(a1[i_] + q));
            }
        }

        if (c + 1 < NCHUNK) {                    // T14: write-late (vmcnt
            *(uint4v*)(bs[(c + 1) & 1] + sdst) = stg;   // hidden under compute)
        }
        mw = mwn;
        __syncthreads();                         // one barrier per chunk
    }

    // ---- combine, sigmoid, store ----
    if (tid < 128) {
        const float z = zl[tid] + bptr[0];
        out[bid * 128 + tid] = 1.0f / (1.0f + EXP2F(-QS * z));
    }
}

// ================================ launcher =================================
extern "C" void kernel_launch(void* const* d_in, const int* in_sizes, int n_in,
                              void* d_out, int out_size, void* d_ws, size_t ws_size,
                              hipStream_t stream) {
    const float* x  = (const float*)d_in[0];   // [K, M]
    const float* xb = (const float*)d_in[1];   // [N, M]
    const float* w  = (const float*)d_in[2];   // [1, N]
    const float* b  = (const float*)d_in[3];   // [1]
    float* out = (float*)d_out;                // [K]

    char*     cb  = (char*)d_ws;                               // 256 KB fp8
    unsigned* hcw = (unsigned*)((char*)d_ws + NCENT * MFEAT);  // 16 KB packed meta

    rbf_prep<<<128 + NCENT / 4, 256, 0, stream>>>(xb, w, cb, hcw);
    rbf_main<<<KOBS / 128, 512, 0, stream>>>(x, cb, hcw, b, out);
}